// Round 1
// baseline (400.204 us; speedup 1.0000x reference)
//
#include <hip/hip_runtime.h>
#include <hip/hip_bf16.h>

#define NNZ 131072
#define MT  1048576
#define EMB 128

typedef __attribute__((ext_vector_type(8))) short  short8;
typedef __attribute__((ext_vector_type(4))) float  floatx4;

__device__ __forceinline__ ushort f2bf(float f) {
    unsigned u = __float_as_uint(f);
    u = (u + 0x7FFFu + ((u >> 16) & 1u)) >> 16;   // RNE
    return (ushort)u;
}

// ---------------------------------------------------------------------------
// Phase 1: X1 = relu(relu(Xv@W10+b10)@W11+b11), X2 likewise with W2*.
// Block = 512 threads (8 waves), 128 rows per block. bf16 MFMA 16x16x32.
// B (weights) packed in LDS in MFMA fragment order; H staged in LDS in
// A-fragment order; A (Xv rows) loaded global->reg.
// ---------------------------------------------------------------------------
__global__ __launch_bounds__(512) void mlp_kernel(
    const float* __restrict__ Xv,
    const float* __restrict__ W10, const float* __restrict__ b10,
    const float* __restrict__ W11, const float* __restrict__ b11,
    const float* __restrict__ W20, const float* __restrict__ b20,
    const float* __restrict__ W21, const float* __restrict__ b21,
    ushort* __restrict__ X1b, ushort* __restrict__ X2b)
{
    __shared__ ushort Wp[16384];   // 128x128 bf16, fragment-packed
    __shared__ ushort Hs[16384];   // per-wave 16x128 bf16 H, A-frag-packed

    const int tid  = threadIdx.x;
    const int wave = tid >> 6;
    const int lane = tid & 63;
    const int g    = lane >> 4;     // k-group 0..3
    const int r    = lane & 15;     // row-in-tile / col-in-tile
    const int rowbase = blockIdx.x * 128 + wave * 16;

    // --- A fragments from Xv (fp32 -> bf16), live whole kernel ---
    short8 af[4];
    const float* xsrc = Xv + (size_t)(rowbase + r) * EMB;
    #pragma unroll
    for (int kt = 0; kt < 4; ++kt) {
        const float4* p = (const float4*)(xsrc + kt * 32 + g * 8);
        float4 v0 = p[0], v1 = p[1];
        short8 a;
        a[0] = (short)f2bf(v0.x); a[1] = (short)f2bf(v0.y);
        a[2] = (short)f2bf(v0.z); a[3] = (short)f2bf(v0.w);
        a[4] = (short)f2bf(v1.x); a[5] = (short)f2bf(v1.y);
        a[6] = (short)f2bf(v1.z); a[7] = (short)f2bf(v1.w);
        af[kt] = a;
    }

    // stage one 128x128 weight matrix into Wp in B-fragment order:
    // slot s = (n*4+kt)*64 + lane ; element j of slot = W[kt*32+(lane/16)*8+j][n*16+lane%16]
    auto stageW = [&](const float* __restrict__ W) {
        for (int s = tid; s < 2048; s += 512) {
            int col  = ((s >> 8) << 4) | (s & 15);
            int krow = (((s >> 6) & 3) << 5) + (((s & 63) >> 4) << 3);
            short8 w;
            #pragma unroll
            for (int j = 0; j < 8; ++j)
                w[j] = (short)f2bf(W[(krow + j) * EMB + col]);
            *(short8*)&Wp[s * 8] = w;
        }
    };

    floatx4 acc[8];
    auto runMFMA = [&](const short8* a4) {
        #pragma unroll
        for (int n = 0; n < 8; ++n) {
            floatx4 c = {0.f, 0.f, 0.f, 0.f};
            #pragma unroll
            for (int kt = 0; kt < 4; ++kt) {
                short8 b = *(const short8*)&Wp[((n * 4 + kt) * 64 + lane) * 8];
                c = __builtin_amdgcn_mfma_f32_16x16x32_bf16(a4[kt], b, c, 0, 0, 0);
            }
            acc[n] = c;
        }
    };

    // write relu(acc+bias) into this wave's H region, A-fragment layout
    auto toH = [&](const float* __restrict__ bias) {
        ushort* hw = Hs + wave * 2048;
        #pragma unroll
        for (int n = 0; n < 8; ++n) {
            float bv = bias[n * 16 + r];
            int col = n * 16 + r;
            int kt = col >> 5, lpg = ((col >> 3) & 3) * 16, j = col & 7;
            #pragma unroll
            for (int q = 0; q < 4; ++q) {
                int row = g * 4 + q;
                float v = fmaxf(acc[n][q] + bv, 0.f);
                hw[(kt * 64 + (row + lpg)) * 8 + j] = f2bf(v);
            }
        }
    };

    auto toG = [&](const float* __restrict__ bias, ushort* __restrict__ dst) {
        #pragma unroll
        for (int n = 0; n < 8; ++n) {
            float bv = bias[n * 16 + r];
            int col = n * 16 + r;
            #pragma unroll
            for (int q = 0; q < 4; ++q) {
                int row = g * 4 + q;
                float v = fmaxf(acc[n][q] + bv, 0.f);
                dst[(size_t)(rowbase + row) * EMB + col] = f2bf(v);
            }
        }
    };

    short8 h4[4];

    // ---- MLP 1 ----
    stageW(W10); __syncthreads();
    runMFMA(af);
    toH(b10);
    __syncthreads();
    stageW(W11); __syncthreads();
    #pragma unroll
    for (int kt = 0; kt < 4; ++kt)
        h4[kt] = *(const short8*)&Hs[wave * 2048 + (kt * 64 + lane) * 8];
    runMFMA(h4);
    toG(b11, X1b);
    __syncthreads();

    // ---- MLP 2 (reuses af) ----
    stageW(W20); __syncthreads();
    runMFMA(af);
    toH(b20);
    __syncthreads();
    stageW(W21); __syncthreads();
    #pragma unroll
    for (int kt = 0; kt < 4; ++kt)
        h4[kt] = *(const short8*)&Hs[wave * 2048 + (kt * 64 + lane) * 8];
    runMFMA(h4);
    toG(b21, X2b);
}

// ---------------------------------------------------------------------------
// Phase 2: CSR build (hist -> scan -> scatter) then segmented gather-reduce.
// ---------------------------------------------------------------------------
__global__ __launch_bounds__(256) void hist_kernel(
    const int* __restrict__ io, int* __restrict__ cnt)
{
    int i = blockIdx.x * 256 + threadIdx.x;
    atomicAdd(&cnt[io[i]], 1);
}

__global__ __launch_bounds__(1024) void scan_kernel(
    const int* __restrict__ cnt, int* __restrict__ ptr)
{
    __shared__ int part[1024];
    int tid = threadIdx.x;
    int base = tid * 128;
    int s = 0;
    for (int j = 0; j < 128; ++j) s += cnt[base + j];
    part[tid] = s;
    __syncthreads();
    for (int off = 1; off < 1024; off <<= 1) {
        int v = (tid >= off) ? part[tid - off] : 0;
        __syncthreads();
        part[tid] += v;
        __syncthreads();
    }
    int run = part[tid] - s;   // exclusive
    for (int j = 0; j < 128; ++j) {
        ptr[base + j] = run;
        run += cnt[base + j];
    }
    if (tid == 1023) ptr[NNZ] = run;
}

__global__ __launch_bounds__(256) void scatter_kernel(
    const int* __restrict__ io, const int* __restrict__ ptr,
    int* __restrict__ cur, int* __restrict__ perm)
{
    int t = blockIdx.x * 256 + threadIdx.x;
    int o = io[t];
    int p = atomicAdd(&cur[o], 1);
    perm[ptr[o] + p] = t;
}

__global__ __launch_bounds__(256) void gather_kernel(
    const ushort* __restrict__ X1b, const ushort* __restrict__ X2b,
    const int* __restrict__ ia, const int* __restrict__ ib,
    const int* __restrict__ ptr, const int* __restrict__ perm,
    float* __restrict__ out)
{
    int o    = blockIdx.x * 4 + (threadIdx.x >> 6);
    int lane = threadIdx.x & 63;
    int beg = ptr[o], end = ptr[o + 1];
    float a0 = 0.f, a1 = 0.f;
    for (int i = beg; i < end; ++i) {
        int t = perm[i];
        int a = ia[t], b = ib[t];
        unsigned u1 = *(const unsigned*)(X1b + (size_t)a * EMB + lane * 2);
        unsigned u2 = *(const unsigned*)(X2b + (size_t)b * EMB + lane * 2);
        a0 += __uint_as_float(u1 << 16) * __uint_as_float(u2 << 16);
        a1 += __uint_as_float(u1 & 0xffff0000u) * __uint_as_float(u2 & 0xffff0000u);
    }
    float2 res = make_float2(a0, a1);
    *(float2*)(out + (size_t)o * EMB + lane * 2) = res;
}

// ---------------------------------------------------------------------------
extern "C" void kernel_launch(void* const* d_in, const int* in_sizes, int n_in,
                              void* d_out, int out_size, void* d_ws, size_t ws_size,
                              hipStream_t stream)
{
    (void)in_sizes; (void)n_in; (void)out_size; (void)ws_size;

    const float* Xv  = (const float*)d_in[0];
    const float* W10 = (const float*)d_in[1];
    const float* b10 = (const float*)d_in[2];
    const float* W11 = (const float*)d_in[3];
    const float* b11 = (const float*)d_in[4];
    const float* W20 = (const float*)d_in[5];
    const float* b20 = (const float*)d_in[6];
    const float* W21 = (const float*)d_in[7];
    const float* b21 = (const float*)d_in[8];
    const int*   ia  = (const int*)d_in[9];
    const int*   ib  = (const int*)d_in[10];
    const int*   io  = (const int*)d_in[11];
    float* out = (float*)d_out;

    char* ws = (char*)d_ws;
    ushort* X1b  = (ushort*)(ws);                       // 32 MB
    ushort* X2b  = (ushort*)(ws + 33554432);            // 32 MB
    int*    cnt  = (int*)(ws + 67108864);               // 512 KB
    int*    ptr  = (int*)(ws + 67633152);               // 512 KB + 4
    int*    cur  = (int*)(ws + 68157696);               // 512 KB
    int*    perm = (int*)(ws + 68681984);               // 4 MB

    hipMemsetAsync(cnt, 0, 524288, stream);
    hipMemsetAsync(cur, 0, 524288, stream);

    mlp_kernel<<<1024, 512, 0, stream>>>(Xv, W10, b10, W11, b11,
                                         W20, b20, W21, b21, X1b, X2b);
    hist_kernel<<<MT / 256, 256, 0, stream>>>(io, cnt);
    scan_kernel<<<1, 1024, 0, stream>>>(cnt, ptr);
    scatter_kernel<<<MT / 256, 256, 0, stream>>>(io, ptr, cur, perm);
    gather_kernel<<<NNZ / 4, 256, 0, stream>>>(X1b, X2b, ia, ib, ptr, perm, out);
}

// Round 2
// 305.733 us; speedup vs baseline: 1.3090x; 1.3090x over previous
//
#include <hip/hip_runtime.h>
#include <hip/hip_bf16.h>

#define NNZ 131072
#define MT  1048576
#define EMB 128

typedef __attribute__((ext_vector_type(8))) short  short8;
typedef __attribute__((ext_vector_type(4))) float  floatx4;

__device__ __forceinline__ ushort f2bf(float f) {
    unsigned u = __float_as_uint(f);
    u = (u + 0x7FFFu + ((u >> 16) & 1u)) >> 16;   // RNE
    return (ushort)u;
}
__device__ __forceinline__ float bf2f(short s) {
    return __uint_as_float(((unsigned)(unsigned short)s) << 16);
}

// ---------------------------------------------------------------------------
// pack weights into B-fragment order (4 matrices) + histogram of ind_out.
// blocks 0..31: pack (8192 slots). blocks 32..4127: hist.
// slot s(0..2047) of matrix L: lane=s&63, nk=s>>6; elem j =
//   W[(nk&3)*32 + (lane>>4)*8 + j][(nk>>2)*16 + (lane&15)]
// ---------------------------------------------------------------------------
__global__ __launch_bounds__(256) void pack_hist_kernel(
    const float* __restrict__ W10, const float* __restrict__ W11,
    const float* __restrict__ W20, const float* __restrict__ W21,
    ushort* __restrict__ Wpk,
    const int* __restrict__ io, int* __restrict__ cnt)
{
    if (blockIdx.x < 32) {
        int s = blockIdx.x * 256 + threadIdx.x;     // 0..8191
        int L = s >> 11, sl = s & 2047;
        const float* W = (L == 0) ? W10 : (L == 1) ? W11 : (L == 2) ? W20 : W21;
        int lane = sl & 63, nk = sl >> 6;
        int col  = (nk >> 2) * 16 + (lane & 15);
        int krow = (nk & 3) * 32 + (lane >> 4) * 8;
        short8 w;
        #pragma unroll
        for (int j = 0; j < 8; ++j)
            w[j] = (short)f2bf(W[(krow + j) * EMB + col]);
        *(short8*)&Wpk[(size_t)s * 8] = w;
    } else {
        int i = (blockIdx.x - 32) * 256 + threadIdx.x;
        atomicAdd(&cnt[io[i]], 1);
    }
}

// ---------------------------------------------------------------------------
// MLP: X1 = relu(relu(Xv@W10+b10)@W11+b11), X2 likewise. 512 thr, 128 rows/blk.
// MFMA called swapped (mfma(Wfrag, Xfrag)) so lane holds row = lane&15,
// cols n*16 + (lane>>4)*4 + q  -> ushort4 LDS writes, coalesced global stores.
// LDS swizzle: byte ^= ((row&3)<<5) ^ ((row&4)<<2).
// ---------------------------------------------------------------------------
__global__ __launch_bounds__(512) void mlp_kernel(
    const float* __restrict__ Xv, const ushort* __restrict__ Wpk,
    const float* __restrict__ b10, const float* __restrict__ b11,
    const float* __restrict__ b20, const float* __restrict__ b21,
    ushort* __restrict__ X1b, ushort* __restrict__ X2b)
{
    __shared__ ushort Wp[16384];           // 32 KB: current-layer weights
    __shared__ ushort Hs[16384];           // 32 KB: 8 waves x 16x128 bf16 bounce

    const int tid  = threadIdx.x;
    const int wave = tid >> 6;
    const int lane = tid & 63;
    const int g    = lane >> 4;
    const int r    = lane & 15;
    const int rowbase = blockIdx.x * 128 + wave * 16;
    char* hw = (char*)(Hs + wave * 2048);  // this wave's 4 KB region

    // A fragments from Xv (row r, k = kt*32 + g*8 + j)
    short8 af[4];
    {
        const float* xsrc = Xv + (size_t)(rowbase + r) * EMB;
        #pragma unroll
        for (int kt = 0; kt < 4; ++kt) {
            const float4* p = (const float4*)(xsrc + kt * 32 + g * 8);
            float4 v0 = p[0], v1 = p[1];
            short8 a;
            a[0] = (short)f2bf(v0.x); a[1] = (short)f2bf(v0.y);
            a[2] = (short)f2bf(v0.z); a[3] = (short)f2bf(v0.w);
            a[4] = (short)f2bf(v1.x); a[5] = (short)f2bf(v1.y);
            a[6] = (short)f2bf(v1.z); a[7] = (short)f2bf(v1.w);
            af[kt] = a;
        }
    }

    auto stageW = [&](int L) {
        const ushort* src = Wpk + (size_t)L * 16384;
        #pragma unroll
        for (int s = tid; s < 2048; s += 512)
            *(short8*)&Wp[s * 8] = *(const short8*)&src[(size_t)s * 8];
    };

    floatx4 acc[8];
    auto runMFMA = [&](const short8* a4) {
        #pragma unroll
        for (int n = 0; n < 8; ++n) {
            floatx4 c = {0.f, 0.f, 0.f, 0.f};
            #pragma unroll
            for (int kt = 0; kt < 4; ++kt) {
                short8 b = *(const short8*)&Wp[((n * 4 + kt) * 64 + lane) * 8];
                c = __builtin_amdgcn_mfma_f32_16x16x32_bf16(b, a4[kt], c, 0, 0, 0);
            }
            acc[n] = c;
        }
    };

    // relu(acc+bias) -> this wave's LDS bounce, swizzled. lane holds row r,
    // cols n*16 + g*4 + {0..3}.
    auto epi = [&](const float* __restrict__ bias) {
        #pragma unroll
        for (int n = 0; n < 8; ++n) {
            float4 bv = *(const float4*)&bias[n * 16 + g * 4];
            ushort4 w;
            w.x = f2bf(fmaxf(acc[n][0] + bv.x, 0.f));
            w.y = f2bf(fmaxf(acc[n][1] + bv.y, 0.f));
            w.z = f2bf(fmaxf(acc[n][2] + bv.z, 0.f));
            w.w = f2bf(fmaxf(acc[n][3] + bv.w, 0.f));
            int byte = r * 256 + n * 32 + g * 8;
            byte ^= ((r & 3) << 5) ^ ((r & 4) << 2);
            *(ushort4*)(hw + byte) = w;
        }
    };

    // read back own bounce as next layer's A fragments
    auto loadH = [&](short8* h4) {
        #pragma unroll
        for (int kt = 0; kt < 4; ++kt) {
            int byte = r * 256 + kt * 64 + g * 16;
            byte ^= ((r & 3) << 5) ^ ((r & 4) << 2);
            h4[kt] = *(const short8*)(hw + byte);
        }
    };

    // read back own bounce, store 1KB/instruction coalesced
    auto storeG = [&](ushort* __restrict__ dst) {
        #pragma unroll
        for (int it = 0; it < 4; ++it) {
            int row  = it * 4 + g;          // g = lane>>4 here rows 0..15
            int byte = row * 256 + (lane & 15) * 16;
            byte ^= ((row & 3) << 5) ^ ((row & 4) << 2);
            short8 v = *(const short8*)(hw + byte);
            *(short8*)&dst[(size_t)rowbase * EMB + row * EMB + (lane & 15) * 8] = v;
        }
    };

    short8 h4[4];

    stageW(0); __syncthreads();
    runMFMA(af); epi(b10); __syncthreads();
    stageW(1); loadH(h4); __syncthreads();
    runMFMA(h4); epi(b11); __syncthreads();
    stageW(2); storeG(X1b); __syncthreads();
    runMFMA(af); epi(b20); __syncthreads();
    stageW(3); loadH(h4); __syncthreads();
    runMFMA(h4); epi(b21); __syncthreads();
    storeG(X2b);
}

// ---------------------------------------------------------------------------
__global__ __launch_bounds__(1024) void scan_kernel(
    const int* __restrict__ cnt, int* __restrict__ ptr)
{
    __shared__ int part[1024];
    int tid = threadIdx.x;
    const int4* c4 = (const int4*)(cnt + tid * 128);
    int s = 0;
    #pragma unroll 8
    for (int j = 0; j < 32; ++j) { int4 v = c4[j]; s += v.x + v.y + v.z + v.w; }
    part[tid] = s;
    __syncthreads();
    for (int off = 1; off < 1024; off <<= 1) {
        int v = (tid >= off) ? part[tid - off] : 0;
        __syncthreads();
        part[tid] += v;
        __syncthreads();
    }
    int run = part[tid] - s;   // exclusive
    int4* p4 = (int4*)(ptr + tid * 128);
    #pragma unroll 8
    for (int j = 0; j < 32; ++j) {
        int4 v = c4[j]; int4 w;
        w.x = run; run += v.x;
        w.y = run; run += v.y;
        w.z = run; run += v.z;
        w.w = run; run += v.w;
        p4[j] = w;
    }
    if (tid == 1023) ptr[NNZ] = run;
}

__global__ __launch_bounds__(256) void scatter_kernel(
    const int* __restrict__ io, const int* __restrict__ ia,
    const int* __restrict__ ib, const int* __restrict__ ptr,
    int* __restrict__ cur, int2* __restrict__ pairs)
{
    int t = blockIdx.x * 256 + threadIdx.x;
    int o = io[t];
    int p = atomicAdd(&cur[o], 1);
    pairs[ptr[o] + p] = make_int2(ia[t], ib[t]);
}

// one wave per output row; 4x16-lane groups, each group = one entry,
// 2 entries deep per group -> 8 row-loads in flight per wave.
__global__ __launch_bounds__(256) void gather_kernel(
    const ushort* __restrict__ X1b, const ushort* __restrict__ X2b,
    const int2* __restrict__ pairs, const int* __restrict__ ptr,
    float* __restrict__ out)
{
    int o    = blockIdx.x * 4 + (threadIdx.x >> 6);
    int lane = threadIdx.x & 63;
    int g = lane >> 4, r = lane & 15;
    int beg = ptr[o], end = ptr[o + 1];
    float acc[8];
    #pragma unroll
    for (int j = 0; j < 8; ++j) acc[j] = 0.f;

    int i = beg + g;
    for (; i + 4 < end; i += 8) {
        int2 p0 = pairs[i];
        int2 p1 = pairs[i + 4];
        short8 x0 = *(const short8*)&X1b[(size_t)p0.x * EMB + r * 8];
        short8 y0 = *(const short8*)&X2b[(size_t)p0.y * EMB + r * 8];
        short8 x1 = *(const short8*)&X1b[(size_t)p1.x * EMB + r * 8];
        short8 y1 = *(const short8*)&X2b[(size_t)p1.y * EMB + r * 8];
        #pragma unroll
        for (int j = 0; j < 8; ++j)
            acc[j] += bf2f(x0[j]) * bf2f(y0[j]) + bf2f(x1[j]) * bf2f(y1[j]);
    }
    if (i < end) {
        int2 p = pairs[i];
        short8 x = *(const short8*)&X1b[(size_t)p.x * EMB + r * 8];
        short8 y = *(const short8*)&X2b[(size_t)p.y * EMB + r * 8];
        #pragma unroll
        for (int j = 0; j < 8; ++j)
            acc[j] += bf2f(x[j]) * bf2f(y[j]);
    }
    #pragma unroll
    for (int j = 0; j < 8; ++j) {
        acc[j] += __shfl_xor(acc[j], 16, 64);
        acc[j] += __shfl_xor(acc[j], 32, 64);
    }
    if (g == 0) {
        float4 v0 = make_float4(acc[0], acc[1], acc[2], acc[3]);
        float4 v1 = make_float4(acc[4], acc[5], acc[6], acc[7]);
        float* dst = out + (size_t)o * EMB + r * 8;
        *(float4*)dst = v0;
        *(float4*)(dst + 4) = v1;
    }
}

// ---------------------------------------------------------------------------
extern "C" void kernel_launch(void* const* d_in, const int* in_sizes, int n_in,
                              void* d_out, int out_size, void* d_ws, size_t ws_size,
                              hipStream_t stream)
{
    (void)in_sizes; (void)n_in; (void)out_size; (void)ws_size;

    const float* Xv  = (const float*)d_in[0];
    const float* W10 = (const float*)d_in[1];
    const float* b10 = (const float*)d_in[2];
    const float* W11 = (const float*)d_in[3];
    const float* b11 = (const float*)d_in[4];
    const float* W20 = (const float*)d_in[5];
    const float* b20 = (const float*)d_in[6];
    const float* W21 = (const float*)d_in[7];
    const float* b21 = (const float*)d_in[8];
    const int*   ia  = (const int*)d_in[9];
    const int*   ib  = (const int*)d_in[10];
    const int*   io  = (const int*)d_in[11];
    float* out = (float*)d_out;

    char* ws = (char*)d_ws;
    size_t off = 0;
    ushort* X1b  = (ushort*)(ws + off); off += 33554432;        // 32 MB
    ushort* X2b  = (ushort*)(ws + off); off += 33554432;        // 32 MB
    ushort* Wpk  = (ushort*)(ws + off); off += 262144;          // 4x2048x8 bf16
    int*    cnt  = (int*)(ws + off);    off += 524288;
    int*    ptr  = (int*)(ws + off);    off += 524416;          // NNZ+1 ints
    int*    cur  = (int*)(ws + off);    off += 524288;
    int2*   pairs= (int2*)(ws + off);   off += 8388608;         // 8 MB

    hipMemsetAsync(cnt, 0, 524288, stream);
    hipMemsetAsync(cur, 0, 524288, stream);

    pack_hist_kernel<<<32 + MT / 256, 256, 0, stream>>>(W10, W11, W20, W21,
                                                        Wpk, io, cnt);
    mlp_kernel<<<1024, 512, 0, stream>>>(Xv, Wpk, b10, b11, b20, b21, X1b, X2b);
    scan_kernel<<<1, 1024, 0, stream>>>(cnt, ptr);
    scatter_kernel<<<MT / 256, 256, 0, stream>>>(io, ia, ib, ptr, cur, pairs);
    gather_kernel<<<NNZ / 4, 256, 0, stream>>>(X1b, X2b, pairs, ptr, out);
}

// Round 3
// 178.036 us; speedup vs baseline: 2.2479x; 1.7173x over previous
//
#include <hip/hip_runtime.h>
#include <hip/hip_bf16.h>

#define NNZ 131072
#define MT  1048576
#define EMB 128
#define CAP 32

typedef __attribute__((ext_vector_type(8))) short  short8;
typedef __attribute__((ext_vector_type(4))) float  floatx4;

__device__ __forceinline__ ushort f2bf(float f) {
    unsigned u = __float_as_uint(f);
    u = (u + 0x7FFFu + ((u >> 16) & 1u)) >> 16;   // RNE
    return (ushort)u;
}

// ---------------------------------------------------------------------------
// pack weights into B-fragment order (blocks 0..31) + optional histogram
// (blocks 32..). In bucket mode launched with grid=32 (pack only).
// ---------------------------------------------------------------------------
__global__ __launch_bounds__(256) void pack_hist_kernel(
    const float* __restrict__ W10, const float* __restrict__ W11,
    const float* __restrict__ W20, const float* __restrict__ W21,
    ushort* __restrict__ Wpk,
    const int* __restrict__ io, int* __restrict__ cnt)
{
    if (blockIdx.x < 32) {
        int s = blockIdx.x * 256 + threadIdx.x;     // 0..8191
        int L = s >> 11, sl = s & 2047;
        const float* W = (L == 0) ? W10 : (L == 1) ? W11 : (L == 2) ? W20 : W21;
        int lane = sl & 63, nk = sl >> 6;
        int col  = (nk >> 2) * 16 + (lane & 15);
        int krow = (nk & 3) * 32 + (lane >> 4) * 8;
        short8 w;
        #pragma unroll
        for (int j = 0; j < 8; ++j)
            w[j] = (short)f2bf(W[(krow + j) * EMB + col]);
        *(short8*)&Wpk[(size_t)s * 8] = w;
    } else {
        int i = (blockIdx.x - 32) * 256 + threadIdx.x;
        atomicAdd(&cnt[io[i]], 1);
    }
}

// ---------------------------------------------------------------------------
// MLP (+ optional fused bucket-scatter with block-parity phase interleave).
// 512 thr, 128 rows/blk, grid must be 1024 when do_scatter=1.
// ---------------------------------------------------------------------------
__global__ __launch_bounds__(512) void mlp_fused(
    const float* __restrict__ Xv, const ushort* __restrict__ Wpk,
    const float* __restrict__ b10, const float* __restrict__ b11,
    const float* __restrict__ b20, const float* __restrict__ b21,
    ushort* __restrict__ X1b, ushort* __restrict__ X2b,
    int do_scatter, const int* __restrict__ io, const int* __restrict__ ia,
    const int* __restrict__ ib, int* __restrict__ cur, int2* __restrict__ pairs)
{
    __shared__ ushort Wp[16384];           // 32 KB: current-layer weights
    __shared__ ushort Hs[16384];           // 32 KB: 8 waves x 16x128 bounce

    const int tid  = threadIdx.x;
    const int wave = tid >> 6;
    const int lane = tid & 63;
    const int g    = lane >> 4;
    const int r    = lane & 15;
    const int rowbase = blockIdx.x * 128 + wave * 16;
    char* hw = (char*)(Hs + wave * 2048);

    auto doScatter = [&]() {
        int base = (int)blockIdx.x * 1024 + tid;
        #pragma unroll
        for (int k = 0; k < 2; ++k) {
            int t = base + k * 512;
            int o = io[t];
            int p = atomicAdd(&cur[o], 1);
            pairs[(size_t)o * CAP + p] = make_int2(ia[t], ib[t]);
        }
    };
    const bool scatFirst = do_scatter && (blockIdx.x & 1);
    if (scatFirst) doScatter();

    // A fragments from Xv (row r, k = kt*32 + g*8 + j)
    short8 af[4];
    {
        const float* xsrc = Xv + (size_t)(rowbase + r) * EMB;
        #pragma unroll
        for (int kt = 0; kt < 4; ++kt) {
            const float4* p = (const float4*)(xsrc + kt * 32 + g * 8);
            float4 v0 = p[0], v1 = p[1];
            short8 a;
            a[0] = (short)f2bf(v0.x); a[1] = (short)f2bf(v0.y);
            a[2] = (short)f2bf(v0.z); a[3] = (short)f2bf(v0.w);
            a[4] = (short)f2bf(v1.x); a[5] = (short)f2bf(v1.y);
            a[6] = (short)f2bf(v1.z); a[7] = (short)f2bf(v1.w);
            af[kt] = a;
        }
    }

    auto stageW = [&](int L) {
        const ushort* src = Wpk + (size_t)L * 16384;
        #pragma unroll
        for (int s = tid; s < 2048; s += 512)
            *(short8*)&Wp[s * 8] = *(const short8*)&src[(size_t)s * 8];
    };

    floatx4 acc[8];
    auto runMFMA = [&](const short8* a4) {
        #pragma unroll
        for (int n = 0; n < 8; ++n) {
            floatx4 c = {0.f, 0.f, 0.f, 0.f};
            #pragma unroll
            for (int kt = 0; kt < 4; ++kt) {
                short8 b = *(const short8*)&Wp[((n * 4 + kt) * 64 + lane) * 8];
                c = __builtin_amdgcn_mfma_f32_16x16x32_bf16(b, a4[kt], c, 0, 0, 0);
            }
            acc[n] = c;
        }
    };

    auto epi = [&](const float* __restrict__ bias) {
        #pragma unroll
        for (int n = 0; n < 8; ++n) {
            float4 bv = *(const float4*)&bias[n * 16 + g * 4];
            ushort4 w;
            w.x = f2bf(fmaxf(acc[n][0] + bv.x, 0.f));
            w.y = f2bf(fmaxf(acc[n][1] + bv.y, 0.f));
            w.z = f2bf(fmaxf(acc[n][2] + bv.z, 0.f));
            w.w = f2bf(fmaxf(acc[n][3] + bv.w, 0.f));
            int byte = r * 256 + n * 32 + g * 8;
            byte ^= ((r & 3) << 5) ^ ((r & 4) << 2);
            *(ushort4*)(hw + byte) = w;
        }
    };

    auto loadH = [&](short8* h4) {
        #pragma unroll
        for (int kt = 0; kt < 4; ++kt) {
            int byte = r * 256 + kt * 64 + g * 16;
            byte ^= ((r & 3) << 5) ^ ((r & 4) << 2);
            h4[kt] = *(const short8*)(hw + byte);
        }
    };

    auto storeG = [&](ushort* __restrict__ dst) {
        #pragma unroll
        for (int it = 0; it < 4; ++it) {
            int row  = it * 4 + g;
            int byte = row * 256 + (lane & 15) * 16;
            byte ^= ((row & 3) << 5) ^ ((row & 4) << 2);
            short8 v = *(const short8*)(hw + byte);
            *(short8*)&dst[(size_t)rowbase * EMB + row * EMB + (lane & 15) * 8] = v;
        }
    };

    short8 h4[4];

    stageW(0); __syncthreads();
    runMFMA(af); epi(b10); __syncthreads();
    stageW(1); loadH(h4); __syncthreads();
    runMFMA(h4); epi(b11); __syncthreads();
    stageW(2); storeG(X1b); __syncthreads();
    runMFMA(af); epi(b20); __syncthreads();
    stageW(3); loadH(h4); __syncthreads();
    runMFMA(h4); epi(b21); __syncthreads();
    storeG(X2b);

    if (do_scatter && !scatFirst) doScatter();
}

// ---------------------------------------------------------------------------
// CSR fallback path kernels (proven round-2 code)
// ---------------------------------------------------------------------------
__global__ __launch_bounds__(1024) void scan_kernel(
    const int* __restrict__ cnt, int* __restrict__ ptr)
{
    __shared__ int part[1024];
    int tid = threadIdx.x;
    const int4* c4 = (const int4*)(cnt + tid * 128);
    int s = 0;
    #pragma unroll 8
    for (int j = 0; j < 32; ++j) { int4 v = c4[j]; s += v.x + v.y + v.z + v.w; }
    part[tid] = s;
    __syncthreads();
    for (int off = 1; off < 1024; off <<= 1) {
        int v = (tid >= off) ? part[tid - off] : 0;
        __syncthreads();
        part[tid] += v;
        __syncthreads();
    }
    int run = part[tid] - s;   // exclusive
    int4* p4 = (int4*)(ptr + tid * 128);
    #pragma unroll 8
    for (int j = 0; j < 32; ++j) {
        int4 v = c4[j]; int4 w;
        w.x = run; run += v.x;
        w.y = run; run += v.y;
        w.z = run; run += v.z;
        w.w = run; run += v.w;
        p4[j] = w;
    }
    if (tid == 1023) ptr[NNZ] = run;
}

__global__ __launch_bounds__(256) void scatter_kernel(
    const int* __restrict__ io, const int* __restrict__ ia,
    const int* __restrict__ ib, const int* __restrict__ ptr,
    int* __restrict__ cur, int2* __restrict__ pairs)
{
    int t = blockIdx.x * 256 + threadIdx.x;
    int o = io[t];
    int p = atomicAdd(&cur[o], 1);
    pairs[ptr[o] + p] = make_int2(ia[t], ib[t]);
}

// ---------------------------------------------------------------------------
// Gather: one wave per output row, lane owns 2 columns. All entries of a
// typical row (<=8) in flight at once; predication via operand zeroing.
// cap!=0: bucket mode (beg=o*cap, end=beg+cnt[o]); cap==0: CSR (ptr).
// ---------------------------------------------------------------------------
__global__ __launch_bounds__(256) void gather_kernel(
    const ushort* __restrict__ X1b, const ushort* __restrict__ X2b,
    const int2* __restrict__ pairs, const int* __restrict__ ptr,
    const int* __restrict__ cnt, int cap, float* __restrict__ out)
{
    int o    = blockIdx.x * 4 + (threadIdx.x >> 6);
    int lane = threadIdx.x & 63;
    int beg, end;
    if (cap) { beg = o * cap; end = beg + cnt[o]; }
    else     { beg = ptr[o];  end = ptr[o + 1]; }
    float ax = 0.f, ay = 0.f;
    for (int base = beg; base < end; base += 8) {
        #pragma unroll
        for (int e = 0; e < 8; ++e) {
            bool ok = (base + e) < end;
            int idx = ok ? base + e : beg;        // beg valid: loop entered
            int2 p = pairs[idx];
            unsigned u1 = *(const unsigned*)(X1b + (size_t)p.x * EMB + lane * 2);
            unsigned u2 = *(const unsigned*)(X2b + (size_t)p.y * EMB + lane * 2);
            if (!ok) u1 = 0u;                      // zero operand -> no-op add
            ax += __uint_as_float(u1 << 16) * __uint_as_float(u2 << 16);
            ay += __uint_as_float(u1 & 0xffff0000u) * __uint_as_float(u2 & 0xffff0000u);
        }
    }
    *(float2*)(out + (size_t)o * EMB + lane * 2) = make_float2(ax, ay);
}

// ---------------------------------------------------------------------------
extern "C" void kernel_launch(void* const* d_in, const int* in_sizes, int n_in,
                              void* d_out, int out_size, void* d_ws, size_t ws_size,
                              hipStream_t stream)
{
    (void)in_sizes; (void)n_in; (void)out_size;

    const float* Xv  = (const float*)d_in[0];
    const float* W10 = (const float*)d_in[1];
    const float* b10 = (const float*)d_in[2];
    const float* W11 = (const float*)d_in[3];
    const float* b11 = (const float*)d_in[4];
    const float* W20 = (const float*)d_in[5];
    const float* b20 = (const float*)d_in[6];
    const float* W21 = (const float*)d_in[7];
    const float* b21 = (const float*)d_in[8];
    const int*   ia  = (const int*)d_in[9];
    const int*   ib  = (const int*)d_in[10];
    const int*   io  = (const int*)d_in[11];
    float* out = (float*)d_out;

    char* ws = (char*)d_ws;
    ushort* X1b  = (ushort*)(ws);                  // 32 MB @ 0
    ushort* X2b  = (ushort*)(ws + 33554432);       // 32 MB
    ushort* Wpk  = (ushort*)(ws + 67108864);       // 256 KB
    int*    cur  = (int*)(ws + 67371008);          // 512 KB
    int*    cnt  = (int*)(ws + 67895296);          // 512 KB (CSR only)
    int*    ptr  = (int*)(ws + 68419584);          // 512 KB + pad (CSR only)
    int2*   pairs= (int2*)(ws + 68944000);         // 32 MB bucket / 8 MB CSR

    const bool bucket = ws_size >= 102498432ULL;   // 68944000 + 32 MB

    hipMemsetAsync(cur, 0, 524288, stream);

    if (bucket) {
        pack_hist_kernel<<<32, 256, 0, stream>>>(W10, W11, W20, W21, Wpk, io, cnt);
        mlp_fused<<<1024, 512, 0, stream>>>(Xv, Wpk, b10, b11, b20, b21,
                                            X1b, X2b, 1, io, ia, ib, cur, pairs);
        gather_kernel<<<NNZ / 4, 256, 0, stream>>>(X1b, X2b, pairs, ptr, cur,
                                                   CAP, out);
    } else {
        hipMemsetAsync(cnt, 0, 524288, stream);
        pack_hist_kernel<<<32 + MT / 256, 256, 0, stream>>>(W10, W11, W20, W21,
                                                            Wpk, io, cnt);
        mlp_fused<<<1024, 512, 0, stream>>>(Xv, Wpk, b10, b11, b20, b21,
                                            X1b, X2b, 0, io, ia, ib, cur, pairs);
        scan_kernel<<<1, 1024, 0, stream>>>(cnt, ptr);
        scatter_kernel<<<MT / 256, 256, 0, stream>>>(io, ia, ib, ptr, cur, pairs);
        gather_kernel<<<NNZ / 4, 256, 0, stream>>>(X1b, X2b, pairs, ptr, cnt,
                                                   0, out);
    }
}